// Round 5
// baseline (554.632 us; speedup 1.0000x reference)
//
#include <hip/hip_runtime.h>

#define NEG_SLOPE 0.2f
#define CHUNK 16384     // edges per bin-block (LDS sort capacity)
#define KMAX  1600      // max buckets (N <= 102400)
#define CAP   3264      // max edges per 64-node bucket (mean 2048, sigma 45)
#define NBLKMAX 256     // max chunks (E <= 4.19M)
#define NDB   49        // dsts per persistent k_gat block (2041 blocks, 8/CU co-resident)

// ---- pass A: chunk-local LDS counting sort by dst-bucket, contiguous SoA write ----
// ssrc[i] = src | (dl<<17)  (src < 2^17, dl = dst&63), seat[i] = eattr, both in
// bucket-sorted order within the chunk. cloff row = per-chunk exclusive bucket offsets.
__global__ __launch_bounds__(1024) void k_bin(const int* __restrict__ ei,
                                              const float* __restrict__ eattr,
                                              int* __restrict__ cloff,
                                              int* __restrict__ ssrc,
                                              float4* __restrict__ seat,
                                              int E, int K) {
    __shared__ int s_off[KMAX + 1];
    __shared__ unsigned s_eid[CHUNK];   // (dl<<14) | e_local, bucket-sorted
    int t = threadIdx.x;
    for (int i = t; i <= K; i += 1024) s_off[i] = 0;
    __syncthreads();
    int base = blockIdx.x * CHUNK;
    int end = min(base + CHUNK, E);
    int Ec = end - base;
    unsigned pack[CHUNK / 1024];
    // phase 1: count + rank (b: 11b, dl: 6b, r: 14b)
#pragma unroll
    for (int i = 0; i < CHUNK / 1024; i++) {
        int el = t + 1024 * i;
        pack[i] = 0xFFFFFFFFu;
        if (el < Ec) {
            int dst = ei[E + base + el];
            int b = dst >> 6;
            int r = atomicAdd(&s_off[b], 1);
            pack[i] = ((unsigned)b << 20) | ((unsigned)(dst & 63) << 14) | (unsigned)r;
        }
    }
    __syncthreads();
    // phase 2: wave0 exclusive-scans s_off over K buckets, in place
    if (t < 64) {
        int run = 0;
        for (int bb = 0; bb < K; bb += 64) {
            int b = bb + t;
            int v = (b < K) ? s_off[b] : 0;
            int x = v;
#pragma unroll
            for (int off = 1; off < 64; off <<= 1) {
                int y = __shfl_up(x, off, 64);
                if (t >= off) x += y;
            }
            if (b < K) s_off[b] = run + x - v;
            run += __shfl(x, 63, 64);
        }
        if (t == 0) s_off[K] = run;
    }
    __syncthreads();
    // phase 3: scatter (dl, e_local) to chunk-sorted LDS position
#pragma unroll
    for (int i = 0; i < CHUNK / 1024; i++) {
        int el = t + 1024 * i;
        if (el < Ec) {
            unsigned p = pack[i];
            int b = p >> 20;
            int r = p & 0x3FFF;
            int dl = (p >> 14) & 63;
            s_eid[s_off[b] + r] = ((unsigned)dl << 14) | (unsigned)el;
        }
    }
    __syncthreads();
    // phase 4: contiguous coalesced write-out of sorted chunk (no write-allocate)
    for (int pos = t; pos < Ec; pos += 1024) {
        unsigned v = s_eid[pos];
        int el = v & 0x3FFF;
        int dl = v >> 14;
        int e = base + el;
        int src = ei[e];
        float4 a = *(const float4*)(eattr + 4ll * e);
        ssrc[base + pos] = src | (dl << 17);
        seat[base + pos] = a;
    }
    // write chunk-local offset row (contiguous)
    for (int i = t; i <= K; i += 1024)
        cloff[(long long)blockIdx.x * (K + 1) + i] = s_off[i];
}

// ---- transpose cloff [NBLK][K+1] -> cloffT [K+1][NBLK] ----
__global__ void k_transp(const int* __restrict__ in, int* __restrict__ out, int R, int C) {
    __shared__ int tile[32][33];
    int c0 = blockIdx.x * 32, r0 = blockIdx.y * 32;
    int c = c0 + threadIdx.x, r = r0 + threadIdx.y;
    if (r < R && c < C) tile[threadIdx.y][threadIdx.x] = in[(long long)r * C + c];
    __syncthreads();
    int oc = r0 + threadIdx.x, orr = c0 + threadIdx.y;
    if (orr < C && oc < R) out[(long long)orr * R + oc] = tile[threadIdx.x][threadIdx.y];
}

// ---- per-bucket totals from cloffT rows ----
__global__ void k_btot(const int* __restrict__ cloffT, int* __restrict__ bucketTotal,
                       int K, int NBLK) {
    int b = (blockIdx.x * blockDim.x + threadIdx.x) >> 6;
    int lane = threadIdx.x & 63;
    if (b >= K) return;
    const int* r0 = cloffT + (long long)b * NBLK;
    const int* r1 = r0 + NBLK;
    int s = 0;
    for (int c = lane; c < NBLK; c += 64) s += r1[c] - r0[c];
#pragma unroll
    for (int off = 32; off >= 1; off >>= 1) s += __shfl_xor(s, off, 64);
    if (lane == 0) bucketTotal[b] = s;
}

// ---- scan bucket slot counts -> slotBase ----
__global__ void k_scanK(const int* __restrict__ bucketTotal, int* __restrict__ slotBase,
                        int* __restrict__ qofs, int N, int K) {
    __shared__ int s[512];
    int t = threadIdx.x;
    int v[4];
    int sum = 0;
    int base = t * 4;
    for (int j = 0; j < 4; j++) {
        int b = base + j, x = 0;
        if (b < K) { int nb = min(64, N - (b << 6)); x = bucketTotal[b] + nb; }
        v[j] = sum;
        sum += x;
    }
    s[t] = sum;
    __syncthreads();
    for (int off = 1; off < 512; off <<= 1) {
        int x = (t >= off) ? s[t - off] : 0;
        __syncthreads();
        s[t] += x;
        __syncthreads();
    }
    int tb = s[t] - sum;
    for (int j = 0; j < 4; j++) {
        int b = base + j;
        if (b < K) slotBase[b] = tb + v[j];
    }
    if (t == 511) { slotBase[K] = s[511]; qofs[4ll * N] = s[511]; }
}

// ---- pass B: per-bucket segment gather -> (dst, src-quarter)-sort -> final CSR ----
// 256-bin counting sort: bin = dl*4 + q, q = src/QDIV (src-slab for L2 cache
// blocking in k_gat). Self-loop goes in its own node's quarter, rank 0 of that
// bin (cur2 pre-seeded). qofs[4*dst+q] = absolute slot of quarter-q start.
__global__ __launch_bounds__(512, 8) void k_perm(const int* __restrict__ ssrc,
                                                 const float4* __restrict__ seat,
                                                 const int* __restrict__ cloffT,
                                                 const int* __restrict__ slotBase,
                                                 int* __restrict__ qofs,
                                                 int* __restrict__ fsrc,
                                                 float4* __restrict__ feat,
                                                 int N, int K, int NBLK, int QDIV) {
    __shared__ int s_pack[CAP];
    __shared__ int s_g[CAP];
    __shared__ int co[NBLKMAX], qq[NBLKMAX + 1], sc[NBLKMAX];
    __shared__ int hist2[256], cur2[256], lst2[256], sc2[256];
    __shared__ int hist[64];
    __shared__ float lsum[64][4];
    int b = blockIdx.x, t = threadIdx.x;
    int nb = min(64, N - (b << 6));
    if (t < 256) { hist2[t] = 0; cur2[t] = 0; }
    if (t < 64) {
        lsum[t][0] = 0.f; lsum[t][1] = 0.f; lsum[t][2] = 0.f; lsum[t][3] = 0.f;
    }
    const int* r0 = cloffT + (long long)b * NBLK;
    const int* r1 = r0 + NBLK;
    int len = 0;
    if (t < NBLKMAX) {
        if (t < NBLK) { int c0v = r0[t]; len = r1[t] - c0v; co[t] = c0v; }
        sc[t] = (t < NBLK) ? len : 0;
    }
    __syncthreads();
    for (int off = 1; off < NBLKMAX; off <<= 1) {
        int x = 0;
        if (t < NBLKMAX && t >= off) x = sc[t - off];
        __syncthreads();
        if (t < NBLKMAX) sc[t] += x;
        __syncthreads();
    }
    if (t < NBLK) qq[t] = sc[t] - len;
    if (t == NBLKMAX - 1) qq[NBLK] = sc[NBLKMAX - 1];
    __syncthreads();
    int Eb = qq[NBLK];
    // phase 1: gather pack words into LDS, histogram by (dl, quarter)
    for (int i = t; i < Eb; i += 512) {
        int lo2 = 0, hi2 = NBLK;
        while (lo2 + 1 < hi2) { int mid = (lo2 + hi2) >> 1; if (qq[mid] <= i) lo2 = mid; else hi2 = mid; }
        int g = lo2 * CHUNK + co[lo2] + (i - qq[lo2]);
        int p = ssrc[g];
        int srcv = p & 0x1FFFF;
        int q = (unsigned)srcv / (unsigned)QDIV;
        s_pack[i] = p | (q << 23);
        s_g[i] = g;
        atomicAdd(&hist2[(((p >> 17) & 63) << 2) | q], 1);
    }
    __syncthreads();
    // pure-edge per-dl counts (for self-loop mean), then add self-loop to its bin
    if (t < 64) {
        int c = hist2[4 * t] + hist2[4 * t + 1] + hist2[4 * t + 2] + hist2[4 * t + 3];
        hist[t] = c;
        if (t < nb) {
            int node = (b << 6) + t;
            int qs = (unsigned)node / (unsigned)QDIV;
            hist2[t * 4 + qs] += 1;           // own bins only: no race
            cur2[t * 4 + qs] = 1;             // self occupies rank 0 of its bin
        }
    }
    __syncthreads();
    // exclusive scan of hist2 over 256 bins
    if (t < 256) sc2[t] = hist2[t];
    __syncthreads();
    for (int off = 1; off < 256; off <<= 1) {
        int x = 0;
        if (t < 256 && t >= off) x = sc2[t - off];
        __syncthreads();
        if (t < 256) sc2[t] += x;
        __syncthreads();
    }
    if (t < 256) lst2[t] = sc2[t] - hist2[t];
    __syncthreads();
    int lo = slotBase[b];
    // write per-(dst, quarter) absolute offsets
    if (t < 256) {
        int dl = t >> 2;
        if (dl < nb)
            qofs[(((long long)((b << 6) + dl)) << 2) + (t & 3)] = lo + lst2[t];
    }
    // phase 3: permute to final slots, eattr global->global + LDS sums
    for (int i = t; i < Eb; i += 512) {
        int p = s_pack[i];
        int dl = (p >> 17) & 63;
        int q = (p >> 23) & 3;
        int srcv = p & 0x1FFFF;
        int bin = (dl << 2) | q;
        int r = atomicAdd(&cur2[bin], 1);
        float4 a = seat[s_g[i]];
        long long pos = lo + lst2[bin] + r;
        fsrc[pos] = srcv;
        feat[pos] = a;
        atomicAdd(&lsum[dl][0], a.x);
        atomicAdd(&lsum[dl][1], a.y);
        atomicAdd(&lsum[dl][2], a.z);
        atomicAdd(&lsum[dl][3], a.w);
    }
    __syncthreads();
    // self-loop slot: mean of incoming eattr (0 if isolated)
    if (t < nb) {
        int node = (b << 6) + t;
        int qs = (unsigned)node / (unsigned)QDIV;
        float inv = 1.f / fmaxf((float)hist[t], 1.f);
        long long pos = lo + lst2[t * 4 + qs];
        fsrc[pos] = node;
        feat[pos] = make_float4(lsum[t][0] * inv, lsum[t][1] * inv,
                                lsum[t][2] * inv, lsum[t][3] * inv);
    }
}

// ---------------- node transforms: xl = x@Wl, xr = x@Wr ----------------
template <int DIN, int D>
__global__ void k_xform(const float* __restrict__ x, const float* __restrict__ Wl,
                        const float* __restrict__ Wr, float* __restrict__ xl,
                        float* __restrict__ xr, int N) {
    __shared__ float sWl[DIN * D], sWr[DIN * D];
    for (int i = threadIdx.x; i < DIN * D; i += blockDim.x) { sWl[i] = Wl[i]; sWr[i] = Wr[i]; }
    __syncthreads();
    int t = blockIdx.x * blockDim.x + threadIdx.x;
    if (t >= N * D) return;
    int n = t / D, d = t % D;
    const float* xp = x + (long long)n * DIN;
    float sl = 0.f, sr = 0.f;
#pragma unroll
    for (int k = 0; k < DIN; k++) {
        float xv = xp[k];
        sl += xv * sWl[k * D + d];
        sr += xv * sWr[k * D + d];
    }
    xl[t] = sl;
    xr[t] = sr;
}

// ---------------- fused GATv2 layer: persistent, src-slab phased ----------------
// 2041 co-resident blocks x 49 dsts. Partial num/den + xr rows in LDS; outer
// loop over NPHASE src-slab phases (quarters of the xl table, 3.2 MB each, L2-
// resident). All blocks walk phases in the same order, so concurrently-running
// waves gather from the same slab -> xl refills become L2 hits. Accumulation is
// wave-private (no atomics, no grid sync; phasing is purely a locality
// heuristic). Softmax is max-free (exp of small scores), so edge order across
// phases is irrelevant. Epilogue (div, bias, relu) fused.
template <int L>
__device__ __forceinline__ void gat_edge(bool valid, const float4& a, const float4& xlv,
                                         const float4& we0, const float4& we1,
                                         const float4& we2, const float4& we3,
                                         const float4& av, const float4& xrv,
                                         float4& acc, float& z) {
    float4 v;
    v.x = fmaf(a.x, we0.x, xrv.x); v.x = fmaf(a.y, we1.x, v.x);
    v.x = fmaf(a.z, we2.x, v.x);   v.x = fmaf(a.w, we3.x, v.x); v.x += xlv.x;
    v.y = fmaf(a.x, we0.y, xrv.y); v.y = fmaf(a.y, we1.y, v.y);
    v.y = fmaf(a.z, we2.y, v.y);   v.y = fmaf(a.w, we3.y, v.y); v.y += xlv.y;
    v.z = fmaf(a.x, we0.z, xrv.z); v.z = fmaf(a.y, we1.z, v.z);
    v.z = fmaf(a.z, we2.z, v.z);   v.z = fmaf(a.w, we3.z, v.z); v.z += xlv.z;
    v.w = fmaf(a.x, we0.w, xrv.w); v.w = fmaf(a.y, we1.w, v.w);
    v.w = fmaf(a.z, we2.w, v.w);   v.w = fmaf(a.w, we3.w, v.w); v.w += xlv.w;
    v.x = v.x > 0.f ? v.x : NEG_SLOPE * v.x;
    v.y = v.y > 0.f ? v.y : NEG_SLOPE * v.y;
    v.z = v.z > 0.f ? v.z : NEG_SLOPE * v.z;
    v.w = v.w > 0.f ? v.w : NEG_SLOPE * v.w;
    float sc = av.x * v.x + av.y * v.y + av.z * v.z + av.w * v.w;
#pragma unroll
    for (int off = L / 2; off >= 1; off >>= 1) sc += __shfl_xor(sc, off, 64);
    float ev = valid ? __expf(sc) : 0.f;
    z += ev;
    acc.x = fmaf(ev, xlv.x, acc.x);
    acc.y = fmaf(ev, xlv.y, acc.y);
    acc.z = fmaf(ev, xlv.z, acc.z);
    acc.w = fmaf(ev, xlv.w, acc.w);
}

template <int D, int NPHASE, bool RELU>
__global__ __launch_bounds__(256, 8) void k_gat(const int* __restrict__ fsrc,
                      const float4* __restrict__ feat,
                      const int* __restrict__ qofs,
                      const float* __restrict__ xl, const float* __restrict__ xr,
                      const float* __restrict__ We, const float* __restrict__ att,
                      const float* __restrict__ bias, float* __restrict__ out, int N) {
    constexpr int L = D / 4;   // lanes per edge
    constexpr int G = 64 / L;  // edges per stage
    __shared__ float part[NDB][D + 4];   // num[D] + den, padded to 16B stride
    __shared__ float xrl[NDB][D];
    int d0 = blockIdx.x * NDB;
    int nd = min(NDB, N - d0);
    int tid = threadIdx.x;
    // stage xr rows (coalesced) + zero partials
    for (int i = tid; i < nd * D; i += 256) xrl[i / D][i % D] = xr[(long long)d0 * D + i];
    for (int i = tid; i < nd * (D + 4); i += 256) part[i / (D + 4)][i % (D + 4)] = 0.f;
    __syncthreads();
    int wv = tid >> 6;
    int lane = tid & 63;
    int g = lane / L;
    int j = lane % L;

    const float4 we0 = *(const float4*)(We + 0 * D + 4 * j);
    const float4 we1 = *(const float4*)(We + 1 * D + 4 * j);
    const float4 we2 = *(const float4*)(We + 2 * D + 4 * j);
    const float4 we3 = *(const float4*)(We + 3 * D + 4 * j);
    const float4 av  = *(const float4*)(att + 4 * j);

    for (int ph = 0; ph < NPHASE; ++ph) {
        int qlo = (4 * ph) / NPHASE;
        int qhi = (4 * (ph + 1)) / NPHASE;
        for (int ld = wv; ld < nd; ld += 4) {
            int d = d0 + ld;
            int s0 = qofs[4 * d + qlo];
            int s1 = qofs[4 * d + qhi];
            int cnt = s1 - s0;
            if (cnt == 0) continue;          // wave-uniform
            float4 xrv = *(const float4*)&xrl[ld][4 * j];
            float4 acc = make_float4(0.f, 0.f, 0.f, 0.f);
            float z = 0.f;
            for (int it = 0; it * G < cnt; ++it) {
                int o = it * G + g;
                bool val = o < cnt;
                int sl = s0 + min(o, cnt - 1);
                int src = fsrc[sl];
                float4 a = feat[sl];
                float4 xlv = *(const float4*)(xl + (long long)src * D + 4 * j);
                gat_edge<L>(val, a, xlv, we0, we1, we2, we3, av, xrv, acc, z);
            }
#pragma unroll
            for (int off = 32; off >= L; off >>= 1) {
                acc.x += __shfl_xor(acc.x, off, 64);
                acc.y += __shfl_xor(acc.y, off, 64);
                acc.z += __shfl_xor(acc.z, off, 64);
                acc.w += __shfl_xor(acc.w, off, 64);
                z += __shfl_xor(z, off, 64);
            }
            if (g == 0) {                    // wave-private RMW: no races
                float4* pp = (float4*)&part[ld][4 * j];
                float4 cp = *pp;
                cp.x += acc.x; cp.y += acc.y; cp.z += acc.z; cp.w += acc.w;
                *pp = cp;
                if (j == 0) part[ld][D] += z;
            }
        }
    }
    // epilogue: out = num/den + bias (, relu) — same wave wrote its partials
    for (int ld = wv; ld < nd; ld += 4) {
        if (g == 0) {
            float inv = 1.f / part[ld][D];
            float4 nm = *(float4*)&part[ld][4 * j];
            float4 bv = *(const float4*)(bias + 4 * j);
            float4 o4;
            o4.x = nm.x * inv + bv.x;
            o4.y = nm.y * inv + bv.y;
            o4.z = nm.z * inv + bv.z;
            o4.w = nm.w * inv + bv.w;
            if (RELU) {
                o4.x = fmaxf(o4.x, 0.f); o4.y = fmaxf(o4.y, 0.f);
                o4.z = fmaxf(o4.z, 0.f); o4.w = fmaxf(o4.w, 0.f);
            }
            *(float4*)(out + (long long)(d0 + ld) * D + 4 * j) = o4;
        }
    }
}

extern "C" void kernel_launch(void* const* d_in, const int* in_sizes, int n_in,
                              void* d_out, int out_size, void* d_ws, size_t ws_size,
                              hipStream_t stream) {
    const float* x     = (const float*)d_in[0];
    const int*   ei    = (const int*)d_in[1];
    const float* eattr = (const float*)d_in[2];
    const float* Wl1   = (const float*)d_in[3];
    const float* Wr1   = (const float*)d_in[4];
    const float* We1   = (const float*)d_in[5];
    const float* att1  = (const float*)d_in[6];
    const float* b1    = (const float*)d_in[7];
    const float* Wl2   = (const float*)d_in[8];
    const float* Wr2   = (const float*)d_in[9];
    const float* We2   = (const float*)d_in[10];
    const float* att2  = (const float*)d_in[11];
    const float* b2    = (const float*)d_in[12];

    const int N = in_sizes[0] / 8;   // 100000
    const int E = in_sizes[1] / 2;   // 3200000
    const int K = (N + 63) >> 6;     // 64-node dst buckets (1563)
    const int NBLK = (E + CHUNK - 1) / CHUNK;   // 196 (<= NBLKMAX)
    const int QDIV = (N + 3) / 4;    // src-slab width (25000 nodes)

    // -------- workspace layout (4B words) --------
    int* iws = (int*)d_ws;
    size_t o = 0;
    int* bucketTotal = iws + o; o += K;
    int* slotBase    = iws + o; o += K + 1;
    int* qofs        = iws + o; o += 4ll * N + 1;
    int* cloff       = iws + o; o += (size_t)NBLK * (K + 1);
    int* cloffT      = iws + o; o += (size_t)(K + 1) * NBLK;
    o = (o + 7) & ~(size_t)7;                              // 32B align
    int*    fsrc = (int*)(iws + o);    o += (size_t)(E + N);
    o = (o + 3) & ~(size_t)3;                              // 16B align
    float4* feat = (float4*)(iws + o); o += 4ll * (E + N);
    // staging region: ssrc+seat, dead after k_perm -> reused for xl/xr/h
    size_t stage = o;
    int*    ssrc = (int*)(iws + o);    o += (size_t)E;
    o = (o + 3) & ~(size_t)3;
    float4* seat = (float4*)(iws + o); o += 4ll * E;
    float* xl = (float*)(iws + stage);           // 32N floats
    float* xr = xl + 32ll * N;
    float* h  = xr + 32ll * N;

    const int B = 256;
    auto cdiv = [](long long a, long long b) { return (int)((a + b - 1) / b); };

    // -------- CSR build: chunk-sort -> (dst, src-quarter) segment permute --------
    k_bin<<<NBLK, 1024, 0, stream>>>(ei, eattr, cloff, ssrc, seat, E, K);
    dim3 tb(32, 32);
    k_transp<<<dim3(cdiv(K + 1, 32), cdiv(NBLK, 32)), tb, 0, stream>>>(cloff, cloffT, NBLK, K + 1);
    k_btot<<<cdiv(64ll * K, B), B, 0, stream>>>(cloffT, bucketTotal, K, NBLK);
    k_scanK<<<1, 512, 0, stream>>>(bucketTotal, slotBase, qofs, N, K);
    k_perm<<<K, 512, 0, stream>>>(ssrc, seat, cloffT, slotBase, qofs, fsrc, feat, N, K, NBLK, QDIV);

    const int GGRID = cdiv(N, NDB);   // 2041 persistent blocks

    // -------- layer 1 (D=32, 4 slab phases of 3.2 MB) --------
    k_xform<8, 32><<<cdiv(32ll * N, B), B, 0, stream>>>(x, Wl1, Wr1, xl, xr, N);
    k_gat<32, 4, true><<<GGRID, B, 0, stream>>>(fsrc, feat, qofs, xl, xr, We1, att1, b1, h, N);

    // -------- layer 2 (D=16, 2 slab phases of 3.2 MB) --------
    k_xform<32, 16><<<cdiv(16ll * N, B), B, 0, stream>>>(h, Wl2, Wr2, xl, xr, N);
    k_gat<16, 2, false><<<GGRID, B, 0, stream>>>(fsrc, feat, qofs, xl, xr, We2, att2, b2, (float*)d_out, N);
}

// Round 6
// 487.858 us; speedup vs baseline: 1.1369x; 1.1369x over previous
//
#include <hip/hip_runtime.h>

#define NEG_SLOPE 0.2f
#define CHUNK 16384     // edges per bin-block (LDS sort capacity)
#define KMAX  1600      // max buckets (N <= 102400)
#define CAP   3264      // max edges per 64-node bucket (mean 2048, sigma 45)
#define NBLKMAX 256     // max chunks (E <= 4.19M)

// ---- pass A: chunk-local LDS counting sort by dst-bucket, contiguous SoA write ----
// ssrc[i] = src | (dl<<17)  (src < 2^17, dl = dst&63), seat[i] = eattr, both in
// bucket-sorted order within the chunk. cloff row = per-chunk exclusive bucket offsets.
__global__ __launch_bounds__(1024) void k_bin(const int* __restrict__ ei,
                                              const float* __restrict__ eattr,
                                              int* __restrict__ cloff,
                                              int* __restrict__ ssrc,
                                              float4* __restrict__ seat,
                                              int E, int K) {
    __shared__ int s_off[KMAX + 1];
    __shared__ unsigned s_eid[CHUNK];   // (dl<<14) | e_local, bucket-sorted
    int t = threadIdx.x;
    for (int i = t; i <= K; i += 1024) s_off[i] = 0;
    __syncthreads();
    int base = blockIdx.x * CHUNK;
    int end = min(base + CHUNK, E);
    int Ec = end - base;
    unsigned pack[CHUNK / 1024];
    // phase 1: count + rank (b: 11b, dl: 6b, r: 14b)
#pragma unroll
    for (int i = 0; i < CHUNK / 1024; i++) {
        int el = t + 1024 * i;
        pack[i] = 0xFFFFFFFFu;
        if (el < Ec) {
            int dst = ei[E + base + el];
            int b = dst >> 6;
            int r = atomicAdd(&s_off[b], 1);
            pack[i] = ((unsigned)b << 20) | ((unsigned)(dst & 63) << 14) | (unsigned)r;
        }
    }
    __syncthreads();
    // phase 2: wave0 exclusive-scans s_off over K buckets, in place
    if (t < 64) {
        int run = 0;
        for (int bb = 0; bb < K; bb += 64) {
            int b = bb + t;
            int v = (b < K) ? s_off[b] : 0;
            int x = v;
#pragma unroll
            for (int off = 1; off < 64; off <<= 1) {
                int y = __shfl_up(x, off, 64);
                if (t >= off) x += y;
            }
            if (b < K) s_off[b] = run + x - v;
            run += __shfl(x, 63, 64);
        }
        if (t == 0) s_off[K] = run;
    }
    __syncthreads();
    // phase 3: scatter (dl, e_local) to chunk-sorted LDS position
#pragma unroll
    for (int i = 0; i < CHUNK / 1024; i++) {
        int el = t + 1024 * i;
        if (el < Ec) {
            unsigned p = pack[i];
            int b = p >> 20;
            int r = p & 0x3FFF;
            int dl = (p >> 14) & 63;
            s_eid[s_off[b] + r] = ((unsigned)dl << 14) | (unsigned)el;
        }
    }
    __syncthreads();
    // phase 4: contiguous coalesced write-out of sorted chunk (no write-allocate)
    for (int pos = t; pos < Ec; pos += 1024) {
        unsigned v = s_eid[pos];
        int el = v & 0x3FFF;
        int dl = v >> 14;
        int e = base + el;
        int src = ei[e];
        float4 a = *(const float4*)(eattr + 4ll * e);
        ssrc[base + pos] = src | (dl << 17);
        seat[base + pos] = a;
    }
    // write chunk-local offset row (contiguous)
    for (int i = t; i <= K; i += 1024)
        cloff[(long long)blockIdx.x * (K + 1) + i] = s_off[i];
}

// ---- transpose cloff [NBLK][K+1] -> cloffT [K+1][NBLK] ----
__global__ void k_transp(const int* __restrict__ in, int* __restrict__ out, int R, int C) {
    __shared__ int tile[32][33];
    int c0 = blockIdx.x * 32, r0 = blockIdx.y * 32;
    int c = c0 + threadIdx.x, r = r0 + threadIdx.y;
    if (r < R && c < C) tile[threadIdx.y][threadIdx.x] = in[(long long)r * C + c];
    __syncthreads();
    int oc = r0 + threadIdx.x, orr = c0 + threadIdx.y;
    if (orr < C && oc < R) out[(long long)orr * R + oc] = tile[threadIdx.x][threadIdx.y];
}

// ---- per-bucket totals from cloffT rows ----
__global__ void k_btot(const int* __restrict__ cloffT, int* __restrict__ bucketTotal,
                       int K, int NBLK) {
    int b = (blockIdx.x * blockDim.x + threadIdx.x) >> 6;
    int lane = threadIdx.x & 63;
    if (b >= K) return;
    const int* r0 = cloffT + (long long)b * NBLK;
    const int* r1 = r0 + NBLK;
    int s = 0;
    for (int c = lane; c < NBLK; c += 64) s += r1[c] - r0[c];
#pragma unroll
    for (int off = 32; off >= 1; off >>= 1) s += __shfl_xor(s, off, 64);
    if (lane == 0) bucketTotal[b] = s;
}

// ---- scan bucket slot counts -> slotBase ----
__global__ void k_scanK(const int* __restrict__ bucketTotal, int* __restrict__ slotBase,
                        int* __restrict__ qofs, int N, int K) {
    __shared__ int s[512];
    int t = threadIdx.x;
    int v[4];
    int sum = 0;
    int base = t * 4;
    for (int j = 0; j < 4; j++) {
        int b = base + j, x = 0;
        if (b < K) { int nb = min(64, N - (b << 6)); x = bucketTotal[b] + nb; }
        v[j] = sum;
        sum += x;
    }
    s[t] = sum;
    __syncthreads();
    for (int off = 1; off < 512; off <<= 1) {
        int x = (t >= off) ? s[t - off] : 0;
        __syncthreads();
        s[t] += x;
        __syncthreads();
    }
    int tb = s[t] - sum;
    for (int j = 0; j < 4; j++) {
        int b = base + j;
        if (b < K) slotBase[b] = tb + v[j];
    }
    if (t == 511) { slotBase[K] = s[511]; qofs[4ll * N] = s[511]; }
}

// ---- pass B: per-bucket segment gather -> (dst, src-quarter)-sort -> final CSR ----
// 256-bin counting sort: bin = dl*4 + q, q = src/QDIV. Each dst's edge run is
// src-quarter-ordered: a wave walking its dst's edges front-to-back touches xl
// slab 0 (3.2 MB, L2-resident) first, then slab 1... Since per-dst edge counts
// are tightly concentrated (~33 +- 6), co-resident waves progress through
// slabs roughly in lockstep -> instantaneous xl working set ~1-2 slabs instead
// of the full 12.8 MB table (round-5 measured: FETCH 340->239 MB), with NO
// per-phase execution overhead (round 5's 158 us mistake).
__global__ __launch_bounds__(512, 8) void k_perm(const int* __restrict__ ssrc,
                                                 const float4* __restrict__ seat,
                                                 const int* __restrict__ cloffT,
                                                 const int* __restrict__ slotBase,
                                                 int* __restrict__ qofs,
                                                 int* __restrict__ fsrc,
                                                 float4* __restrict__ feat,
                                                 int N, int K, int NBLK, int QDIV) {
    __shared__ int s_pack[CAP];
    __shared__ int s_g[CAP];
    __shared__ int co[NBLKMAX], qq[NBLKMAX + 1], sc[NBLKMAX];
    __shared__ int hist2[256], cur2[256], lst2[256], sc2[256];
    __shared__ int hist[64];
    __shared__ float lsum[64][4];
    int b = blockIdx.x, t = threadIdx.x;
    int nb = min(64, N - (b << 6));
    if (t < 256) { hist2[t] = 0; cur2[t] = 0; }
    if (t < 64) {
        lsum[t][0] = 0.f; lsum[t][1] = 0.f; lsum[t][2] = 0.f; lsum[t][3] = 0.f;
    }
    const int* r0 = cloffT + (long long)b * NBLK;
    const int* r1 = r0 + NBLK;
    int len = 0;
    if (t < NBLKMAX) {
        if (t < NBLK) { int c0v = r0[t]; len = r1[t] - c0v; co[t] = c0v; }
        sc[t] = (t < NBLK) ? len : 0;
    }
    __syncthreads();
    for (int off = 1; off < NBLKMAX; off <<= 1) {
        int x = 0;
        if (t < NBLKMAX && t >= off) x = sc[t - off];
        __syncthreads();
        if (t < NBLKMAX) sc[t] += x;
        __syncthreads();
    }
    if (t < NBLK) qq[t] = sc[t] - len;
    if (t == NBLKMAX - 1) qq[NBLK] = sc[NBLKMAX - 1];
    __syncthreads();
    int Eb = qq[NBLK];
    // phase 1: gather pack words into LDS, histogram by (dl, quarter)
    for (int i = t; i < Eb; i += 512) {
        int lo2 = 0, hi2 = NBLK;
        while (lo2 + 1 < hi2) { int mid = (lo2 + hi2) >> 1; if (qq[mid] <= i) lo2 = mid; else hi2 = mid; }
        int g = lo2 * CHUNK + co[lo2] + (i - qq[lo2]);
        int p = ssrc[g];
        int srcv = p & 0x1FFFF;
        int q = (unsigned)srcv / (unsigned)QDIV;
        s_pack[i] = p | (q << 23);
        s_g[i] = g;
        atomicAdd(&hist2[(((p >> 17) & 63) << 2) | q], 1);
    }
    __syncthreads();
    // pure-edge per-dl counts (for self-loop mean), then add self-loop to its bin
    if (t < 64) {
        int c = hist2[4 * t] + hist2[4 * t + 1] + hist2[4 * t + 2] + hist2[4 * t + 3];
        hist[t] = c;
        if (t < nb) {
            int node = (b << 6) + t;
            int qs = (unsigned)node / (unsigned)QDIV;
            hist2[t * 4 + qs] += 1;           // own bins only: no race
            cur2[t * 4 + qs] = 1;             // self occupies rank 0 of its bin
        }
    }
    __syncthreads();
    // exclusive scan of hist2 over 256 bins
    if (t < 256) sc2[t] = hist2[t];
    __syncthreads();
    for (int off = 1; off < 256; off <<= 1) {
        int x = 0;
        if (t < 256 && t >= off) x = sc2[t - off];
        __syncthreads();
        if (t < 256) sc2[t] += x;
        __syncthreads();
    }
    if (t < 256) lst2[t] = sc2[t] - hist2[t];
    __syncthreads();
    int lo = slotBase[b];
    // write per-(dst, quarter) absolute offsets
    if (t < 256) {
        int dl = t >> 2;
        if (dl < nb)
            qofs[(((long long)((b << 6) + dl)) << 2) + (t & 3)] = lo + lst2[t];
    }
    // phase 3: permute to final slots, eattr global->global + LDS sums
    for (int i = t; i < Eb; i += 512) {
        int p = s_pack[i];
        int dl = (p >> 17) & 63;
        int q = (p >> 23) & 3;
        int srcv = p & 0x1FFFF;
        int bin = (dl << 2) | q;
        int r = atomicAdd(&cur2[bin], 1);
        float4 a = seat[s_g[i]];
        long long pos = lo + lst2[bin] + r;
        fsrc[pos] = srcv;
        feat[pos] = a;
        atomicAdd(&lsum[dl][0], a.x);
        atomicAdd(&lsum[dl][1], a.y);
        atomicAdd(&lsum[dl][2], a.z);
        atomicAdd(&lsum[dl][3], a.w);
    }
    __syncthreads();
    // self-loop slot: mean of incoming eattr (0 if isolated)
    if (t < nb) {
        int node = (b << 6) + t;
        int qs = (unsigned)node / (unsigned)QDIV;
        float inv = 1.f / fmaxf((float)hist[t], 1.f);
        long long pos = lo + lst2[t * 4 + qs];
        fsrc[pos] = node;
        feat[pos] = make_float4(lsum[t][0] * inv, lsum[t][1] * inv,
                                lsum[t][2] * inv, lsum[t][3] * inv);
    }
}

// ---------------- node transforms: xl = x@Wl, xr = x@Wr ----------------
template <int DIN, int D>
__global__ void k_xform(const float* __restrict__ x, const float* __restrict__ Wl,
                        const float* __restrict__ Wr, float* __restrict__ xl,
                        float* __restrict__ xr, int N) {
    __shared__ float sWl[DIN * D], sWr[DIN * D];
    for (int i = threadIdx.x; i < DIN * D; i += blockDim.x) { sWl[i] = Wl[i]; sWr[i] = Wr[i]; }
    __syncthreads();
    int t = blockIdx.x * blockDim.x + threadIdx.x;
    if (t >= N * D) return;
    int n = t / D, d = t % D;
    const float* xp = x + (long long)n * DIN;
    float sl = 0.f, sr = 0.f;
#pragma unroll
    for (int k = 0; k < DIN; k++) {
        float xv = xp[k];
        sl += xv * sWl[k * D + d];
        sr += xv * sWr[k * D + d];
    }
    xl[t] = sl;
    xr[t] = sr;
}

// ---------------- fused GATv2 layer: wave per dst, float4 per lane ----------------
// Round-3 structure (measured 100.4 us L1): pair-unroll with clamped singles.
// Edge runs are src-quarter-sorted (see k_perm) for implicit slab locality.
template <int L>
__device__ __forceinline__ void gat_edge(bool valid, const float4& a, const float4& xlv,
                                         const float4& we0, const float4& we1,
                                         const float4& we2, const float4& we3,
                                         const float4& av, const float4& xrv,
                                         float4& acc, float& z) {
    float4 v;
    v.x = fmaf(a.x, we0.x, xrv.x); v.x = fmaf(a.y, we1.x, v.x);
    v.x = fmaf(a.z, we2.x, v.x);   v.x = fmaf(a.w, we3.x, v.x); v.x += xlv.x;
    v.y = fmaf(a.x, we0.y, xrv.y); v.y = fmaf(a.y, we1.y, v.y);
    v.y = fmaf(a.z, we2.y, v.y);   v.y = fmaf(a.w, we3.y, v.y); v.y += xlv.y;
    v.z = fmaf(a.x, we0.z, xrv.z); v.z = fmaf(a.y, we1.z, v.z);
    v.z = fmaf(a.z, we2.z, v.z);   v.z = fmaf(a.w, we3.z, v.z); v.z += xlv.z;
    v.w = fmaf(a.x, we0.w, xrv.w); v.w = fmaf(a.y, we1.w, v.w);
    v.w = fmaf(a.z, we2.w, v.w);   v.w = fmaf(a.w, we3.w, v.w); v.w += xlv.w;
    v.x = v.x > 0.f ? v.x : NEG_SLOPE * v.x;
    v.y = v.y > 0.f ? v.y : NEG_SLOPE * v.y;
    v.z = v.z > 0.f ? v.z : NEG_SLOPE * v.z;
    v.w = v.w > 0.f ? v.w : NEG_SLOPE * v.w;
    float sc = av.x * v.x + av.y * v.y + av.z * v.z + av.w * v.w;
#pragma unroll
    for (int off = L / 2; off >= 1; off >>= 1) sc += __shfl_xor(sc, off, 64);
    float ev = valid ? __expf(sc) : 0.f;
    z += ev;
    acc.x = fmaf(ev, xlv.x, acc.x);
    acc.y = fmaf(ev, xlv.y, acc.y);
    acc.z = fmaf(ev, xlv.z, acc.z);
    acc.w = fmaf(ev, xlv.w, acc.w);
}

template <int D, bool RELU>
__global__ void k_gat(const int* __restrict__ fsrc,
                      const float4* __restrict__ feat,
                      const int* __restrict__ qofs,
                      const float* __restrict__ xl, const float* __restrict__ xr,
                      const float* __restrict__ We, const float* __restrict__ att,
                      const float* __restrict__ bias, float* __restrict__ out, int N) {
    constexpr int L = D / 4;   // lanes per edge
    constexpr int G = 64 / L;  // edges per stage
    int w = (blockIdx.x * blockDim.x + threadIdx.x) >> 6;
    int lane = threadIdx.x & 63;
    if (w >= N) return;
    int g = lane / L;
    int j = lane % L;
    int s0 = qofs[4 * w], s1 = qofs[4 * w + 4];
    int cnt = s1 - s0;    // >= 1 (self-loop)

    const float4 we0 = *(const float4*)(We + 0 * D + 4 * j);
    const float4 we1 = *(const float4*)(We + 1 * D + 4 * j);
    const float4 we2 = *(const float4*)(We + 2 * D + 4 * j);
    const float4 we3 = *(const float4*)(We + 3 * D + 4 * j);
    const float4 av  = *(const float4*)(att + 4 * j);
    const float4 xrv = *(const float4*)(xr + (long long)w * D + 4 * j);

    float4 acc = make_float4(0.f, 0.f, 0.f, 0.f);
    float z = 0.f;

    int it = 0;
    // ---- pair stages (all lanes valid): 2 independent xl gathers in flight ----
    for (; (it + 2) * G <= cnt; it += 2) {
        int sl = s0 + it * G + g;
        int srcA = fsrc[sl];
        int srcB = fsrc[sl + G];
        float4 aA = feat[sl];
        float4 aB = feat[sl + G];
        float4 xA = *(const float4*)(xl + (long long)srcA * D + 4 * j);
        float4 xB = *(const float4*)(xl + (long long)srcB * D + 4 * j);
        gat_edge<L>(true, aA, xA, we0, we1, we2, we3, av, xrv, acc, z);
        gat_edge<L>(true, aB, xB, we0, we1, we2, we3, av, xrv, acc, z);
    }
    // ---- remaining (<=2) single stages, clamped predication ----
    for (; it * G < cnt; ++it) {
        int o = it * G + g;
        bool v = o < cnt;
        int sl = s0 + min(o, cnt - 1);
        int src = fsrc[sl];
        float4 a = feat[sl];
        float4 xv = *(const float4*)(xl + (long long)src * D + 4 * j);
        gat_edge<L>(v, a, xv, we0, we1, we2, we3, av, xrv, acc, z);
    }

#pragma unroll
    for (int off = 32; off >= L; off >>= 1) {
        acc.x += __shfl_xor(acc.x, off, 64);
        acc.y += __shfl_xor(acc.y, off, 64);
        acc.z += __shfl_xor(acc.z, off, 64);
        acc.w += __shfl_xor(acc.w, off, 64);
        z += __shfl_xor(z, off, 64);
    }

    if (g == 0) {
        float inv = 1.0f / z;
        float4 bv = *(const float4*)(bias + 4 * j);
        float4 o;
        o.x = acc.x * inv + bv.x;
        o.y = acc.y * inv + bv.y;
        o.z = acc.z * inv + bv.z;
        o.w = acc.w * inv + bv.w;
        if (RELU) {
            o.x = fmaxf(o.x, 0.f); o.y = fmaxf(o.y, 0.f);
            o.z = fmaxf(o.z, 0.f); o.w = fmaxf(o.w, 0.f);
        }
        *(float4*)(out + (long long)w * D + 4 * j) = o;
    }
}

extern "C" void kernel_launch(void* const* d_in, const int* in_sizes, int n_in,
                              void* d_out, int out_size, void* d_ws, size_t ws_size,
                              hipStream_t stream) {
    const float* x     = (const float*)d_in[0];
    const int*   ei    = (const int*)d_in[1];
    const float* eattr = (const float*)d_in[2];
    const float* Wl1   = (const float*)d_in[3];
    const float* Wr1   = (const float*)d_in[4];
    const float* We1   = (const float*)d_in[5];
    const float* att1  = (const float*)d_in[6];
    const float* b1    = (const float*)d_in[7];
    const float* Wl2   = (const float*)d_in[8];
    const float* Wr2   = (const float*)d_in[9];
    const float* We2   = (const float*)d_in[10];
    const float* att2  = (const float*)d_in[11];
    const float* b2    = (const float*)d_in[12];

    const int N = in_sizes[0] / 8;   // 100000
    const int E = in_sizes[1] / 2;   // 3200000
    const int K = (N + 63) >> 6;     // 64-node dst buckets (1563)
    const int NBLK = (E + CHUNK - 1) / CHUNK;   // 196 (<= NBLKMAX)
    const int QDIV = (N + 3) / 4;    // src-slab width (25000 nodes)

    // -------- workspace layout (4B words) --------
    int* iws = (int*)d_ws;
    size_t o = 0;
    int* bucketTotal = iws + o; o += K;
    int* slotBase    = iws + o; o += K + 1;
    int* qofs        = iws + o; o += 4ll * N + 1;
    int* cloff       = iws + o; o += (size_t)NBLK * (K + 1);
    int* cloffT      = iws + o; o += (size_t)(K + 1) * NBLK;
    o = (o + 7) & ~(size_t)7;                              // 32B align
    int*    fsrc = (int*)(iws + o);    o += (size_t)(E + N);
    o = (o + 3) & ~(size_t)3;                              // 16B align
    float4* feat = (float4*)(iws + o); o += 4ll * (E + N);
    // staging region: ssrc+seat, dead after k_perm -> reused for xl/xr/h
    size_t stage = o;
    int*    ssrc = (int*)(iws + o);    o += (size_t)E;
    o = (o + 3) & ~(size_t)3;
    float4* seat = (float4*)(iws + o); o += 4ll * E;
    float* xl = (float*)(iws + stage);           // 32N floats
    float* xr = xl + 32ll * N;
    float* h  = xr + 32ll * N;

    const int B = 256;
    auto cdiv = [](long long a, long long b) { return (int)((a + b - 1) / b); };

    // -------- CSR build: chunk-sort -> (dst, src-quarter) segment permute --------
    k_bin<<<NBLK, 1024, 0, stream>>>(ei, eattr, cloff, ssrc, seat, E, K);
    dim3 tb(32, 32);
    k_transp<<<dim3(cdiv(K + 1, 32), cdiv(NBLK, 32)), tb, 0, stream>>>(cloff, cloffT, NBLK, K + 1);
    k_btot<<<cdiv(64ll * K, B), B, 0, stream>>>(cloffT, bucketTotal, K, NBLK);
    k_scanK<<<1, 512, 0, stream>>>(bucketTotal, slotBase, qofs, N, K);
    k_perm<<<K, 512, 0, stream>>>(ssrc, seat, cloffT, slotBase, qofs, fsrc, feat, N, K, NBLK, QDIV);

    // -------- layer 1 (D=32) --------
    k_xform<8, 32><<<cdiv(32ll * N, B), B, 0, stream>>>(x, Wl1, Wr1, xl, xr, N);
    k_gat<32, true><<<cdiv(N, 4), B, 0, stream>>>(fsrc, feat, qofs, xl, xr, We1, att1, b1, h, N);

    // -------- layer 2 (D=16) --------
    k_xform<32, 16><<<cdiv(16ll * N, B), B, 0, stream>>>(h, Wl2, Wr2, xl, xr, N);
    k_gat<16, false><<<cdiv(N, 4), B, 0, stream>>>(fsrc, feat, qofs, xl, xr, We2, att2, b2, (float*)d_out, N);
}